// Round 1
// baseline (6314.917 us; speedup 1.0000x reference)
//
#include <hip/hip_runtime.h>
#include <hip/hip_bf16.h>
#include <math.h>

#define BB 32
#define LL 12
#define NN 512
#define DD 128
#define BN 16384
#define HH 4
#define TT 12
#define FKK 256
#define NSLOT 23

// ---------------------------------------------------------------------------
// helpers
// ---------------------------------------------------------------------------
__device__ __forceinline__ float selv(const float4& v, int j) {
    return (j == 0) ? v.x : ((j == 1) ? v.y : ((j == 2) ? v.z : v.w));
}

// Stage 64 rows x 128 cols of a K-contiguous matrix, transposed, into sT[k][m].
// Row address = base + (row/512)*outer + (row%512)*128  (outer=65536 => contiguous).
// Rotated writes (j depends on tid>>3) keep LDS write conflicts ~2-way.
__device__ __forceinline__ void stage64(float (*sT)[68], const float* base,
                                        long outer, int row0, int tid,
                                        const float* addrow) {
    int sm  = tid & 7;
    int skg = tid >> 3;      // 0..31
    int sk  = skg << 2;      // 0,4,...,124
#pragma unroll
    for (int i = 0; i < 8; ++i) {
        int m   = sm + i * 8;
        int row = row0 + m;
        const float4 v = *(const float4*)(base + (long)(row >> 9) * outer +
                                          (long)(row & 511) * 128 + sk);
#pragma unroll
        for (int jj = 0; jj < 4; ++jj) {
            int j = (jj + skg) & 3;
            float val = selv(v, j);
            if (addrow) val += addrow[sk + j];
            sT[sk + j][m] = val;
        }
    }
}

// 64x64 outer-product pass over K=128: acc[4][4] += A^T * B
__device__ __forceinline__ void mm128(const float (*aT)[68], const float (*bT)[68],
                                      int tm4, int tn4, float (&acc)[4][4]) {
#pragma unroll 8
    for (int k = 0; k < 128; ++k) {
        const float4 a = *(const float4*)&aT[k][tm4];
        const float4 b = *(const float4*)&bT[k][tn4];
        acc[0][0] += a.x * b.x; acc[0][1] += a.x * b.y; acc[0][2] += a.x * b.z; acc[0][3] += a.x * b.w;
        acc[1][0] += a.y * b.x; acc[1][1] += a.y * b.y; acc[1][2] += a.y * b.z; acc[1][3] += a.y * b.w;
        acc[2][0] += a.z * b.x; acc[2][1] += a.z * b.y; acc[2][2] += a.z * b.z; acc[2][3] += a.z * b.w;
        acc[3][0] += a.w * b.x; acc[3][1] += a.w * b.y; acc[3][2] += a.w * b.z; acc[3][3] += a.w * b.w;
    }
}

// ---------------------------------------------------------------------------
// PE tables: pe[p][d], and pe @ {Wq,Wk,Wv}^T (no bias)
// ---------------------------------------------------------------------------
__global__ __launch_bounds__(128) void pe_init(const float* __restrict__ Wqkv,
                                               float* __restrict__ pe,
                                               float* __restrict__ peq,
                                               float* __restrict__ pek,
                                               float* __restrict__ pev) {
    int p = blockIdx.x, d = threadIdx.x;
    __shared__ float per[128];
    int i2 = (d >> 1) << 1;  // 2*i
    float dv  = expf(-(float)i2 * 0.0719557841560639f);  // ln(10000)/128
    float arg = (float)p * dv;
    per[d] = (d & 1) ? cosf(arg) : sinf(arg);
    __syncthreads();
    pe[p * 128 + d] = per[d];
    float sq = 0.f, sk = 0.f, sv = 0.f;
    for (int k = 0; k < 128; ++k) {
        float pv = per[k];
        sq += pv * Wqkv[d * 128 + k];
        sk += pv * Wqkv[(128 + d) * 128 + k];
        sv += pv * Wqkv[(256 + d) * 128 + k];
    }
    peq[p * 128 + d] = sq;
    pek[p * 128 + d] = sk;
    pev[p * 128 + d] = sv;
}

// ---------------------------------------------------------------------------
// Generic GEMM: C = A @ W^T + bias.  A rows via (chunk512,outer) mapping.
// Output column groups of 128 routed to C0/C1/C2 (for fused QKV).
// ---------------------------------------------------------------------------
__global__ __launch_bounds__(256) void gemm_k128(
    const float* __restrict__ A, long a_outer,
    const float* __restrict__ W, const float* __restrict__ bias,
    float* __restrict__ C0, float* __restrict__ C1, float* __restrict__ C2,
    long c_outer, int c_inner) {
    __shared__ float aT[128][68];
    __shared__ float wT[128][68];
    int tid  = threadIdx.x;
    int mblk = blockIdx.x * 64;
    int nblk = blockIdx.y * 64;
    stage64(aT, A, a_outer, mblk, tid, nullptr);
    stage64(wT, W, 0, nblk, tid, nullptr);
    __syncthreads();
    float acc[4][4] = {};
    int tn4 = (tid & 15) << 2;
    int tm4 = (tid >> 4) << 2;
    mm128(aT, wT, tm4, tn4, acc);
    int cb = nblk + tn4;
    const float4 b4 = *(const float4*)(bias + cb);
    float* Cp = (cb >= 256) ? C2 : ((cb >= 128) ? C1 : C0);
    int cc = cb & 127;
#pragma unroll
    for (int im = 0; im < 4; ++im) {
        int row = mblk + tm4 + im;
        float4 o = make_float4(acc[im][0] + b4.x, acc[im][1] + b4.y,
                               acc[im][2] + b4.z, acc[im][3] + b4.w);
        *(float4*)(Cp + (long)(row >> 9) * c_outer + (long)(row & 511) * c_inner + cc) = o;
    }
}

// ---------------------------------------------------------------------------
// Fused GRU step: h' = (1-z)*n + z*h,  r/z/n = torch GRUCell math.
// Computes gi = x@Wih^T and gh = h@Whh^T in 6 LDS passes, combines in-register.
// ---------------------------------------------------------------------------
template <bool HZERO, bool HADD>
__global__ __launch_bounds__(256) void gru_step(
    const float* __restrict__ Xb, long x_outer,
    const float* __restrict__ Hb, const float* __restrict__ hadd,
    const float* __restrict__ Wih, const float* __restrict__ Whh,
    const float* __restrict__ bih, const float* __restrict__ bhh,
    float* __restrict__ Hout) {
    __shared__ float xT[128][68];
    __shared__ float hT[128][68];
    __shared__ float wT[128][68];
    int tid  = threadIdx.x;
    int mblk = blockIdx.x * 64;
    int dblk = blockIdx.y * 64;
    stage64(xT, Xb, x_outer, mblk, tid, nullptr);
    if (!HZERO) stage64(hT, Hb, 65536, mblk, tid, HADD ? hadd : nullptr);
    int tn4 = (tid & 15) << 2;
    int tm4 = (tid >> 4) << 2;
    float acc[3][2][4][4] = {};
#pragma unroll
    for (int g = 0; g < 3; ++g) {
        __syncthreads();
        stage64(wT, Wih, 0, g * 128 + dblk, tid, nullptr);
        __syncthreads();
        mm128(xT, wT, tm4, tn4, acc[g][0]);
        if (!HZERO) {
            __syncthreads();
            stage64(wT, Whh, 0, g * 128 + dblk, tid, nullptr);
            __syncthreads();
            mm128(hT, wT, tm4, tn4, acc[g][1]);
        }
    }
#define GRU_COMB(JD, DEST)                                                        \
    {                                                                             \
        int d = dblk + tn4 + JD;                                                  \
        float hprev = HZERO ? 0.f : hT[d][tm4 + im];                              \
        float rr = acc[0][0][im][JD] + bih[d] + bhh[d] +                          \
                   (HZERO ? 0.f : acc[0][1][im][JD]);                             \
        float r = 1.f / (1.f + expf(-rr));                                        \
        float zz = acc[1][0][im][JD] + bih[128 + d] + bhh[128 + d] +              \
                   (HZERO ? 0.f : acc[1][1][im][JD]);                             \
        float z = 1.f / (1.f + expf(-zz));                                        \
        float hn = bhh[256 + d] + (HZERO ? 0.f : acc[2][1][im][JD]);              \
        float n = tanhf(acc[2][0][im][JD] + bih[256 + d] + r * hn);               \
        DEST = (1.f - z) * n + z * hprev;                                         \
    }
#pragma unroll
    for (int im = 0; im < 4; ++im) {
        int row = mblk + tm4 + im;
        float o0, o1, o2, o3;
        GRU_COMB(0, o0) GRU_COMB(1, o1) GRU_COMB(2, o2) GRU_COMB(3, o3)
        *(float4*)(Hout + (long)row * 128 + dblk + tn4) = make_float4(o0, o1, o2, o3);
    }
#undef GRU_COMB
}

// ---------------------------------------------------------------------------
// Z0 self-attention (L=12 x L=12), PE folded in via precomputed pe-projections.
// One block per bn.  AO may alias Q (block touches only its own bn rows).
// ---------------------------------------------------------------------------
__global__ __launch_bounds__(256) void attn_z0(
    const float* Q, const float* __restrict__ K, const float* __restrict__ V,
    const float* __restrict__ peq, const float* __restrict__ pek,
    const float* __restrict__ pev, float* AO) {
    int bn = blockIdx.x, tid = threadIdx.x;
    __shared__ float Qs[12][132], Ks[12][132], Vs[12][132];
    __shared__ float sc[4][12][12];
    for (int idx = tid; idx < 12 * 128; idx += 256) {
        int t = idx >> 7, d = idx & 127;
        long g = ((long)(t * BN + bn) << 7) + d;
        Qs[t][d] = Q[g] + peq[t * 128 + d];
        Ks[t][d] = K[g] + pek[t * 128 + d];
        Vs[t][d] = V[g] + pev[t * 128 + d];
    }
    __syncthreads();
    for (int idx = tid; idx < 576; idx += 256) {
        int h = idx / 144, r = idx - h * 144;
        int q = r / 12, k = r - (r / 12) * 12;
        float s = 0.f;
#pragma unroll
        for (int d = 0; d < 32; ++d) s += Qs[q][h * 32 + d] * Ks[k][h * 32 + d];
        sc[h][q][k] = s * 0.17677669529663687f;
    }
    __syncthreads();
    if (tid < 48) {
        int h = tid / 12, q = tid - (tid / 12) * 12;
        float mx = sc[h][q][0];
#pragma unroll
        for (int k = 1; k < 12; ++k) mx = fmaxf(mx, sc[h][q][k]);
        float sum = 0.f;
#pragma unroll
        for (int k = 0; k < 12; ++k) { float e = expf(sc[h][q][k] - mx); sc[h][q][k] = e; sum += e; }
        float inv = 1.f / sum;
#pragma unroll
        for (int k = 0; k < 12; ++k) sc[h][q][k] *= inv;
    }
    __syncthreads();
    for (int idx = tid; idx < 1536; idx += 256) {
        int q = idx >> 7, d = idx & 127, h = d >> 5;
        float s = 0.f;
#pragma unroll
        for (int k = 0; k < 12; ++k) s += sc[h][q][k] * Vs[k][d];
        AO[((long)(q * BN + bn) << 7) + d] = s;
    }
}

// ---------------------------------------------------------------------------
// Decode attention: 1 query vs NK keys, k_j = K_base[j] + c_j*pek[j],
// c_j = min(iter+1, 13+iter-j) encodes the cumulative PE re-additions.
// ---------------------------------------------------------------------------
__global__ __launch_bounds__(256) void attn_dec(
    const float* __restrict__ Qg, const float* __restrict__ K,
    const float* __restrict__ V, const float* __restrict__ pek,
    const float* __restrict__ pev, float* __restrict__ AOd, int NK, int iter) {
    int bn = blockIdx.x, tid = threadIdx.x;
    __shared__ float qs[128];
    __shared__ float Ks[NSLOT][132], Vs[NSLOT][132];
    __shared__ float sc[4][NSLOT];
    if (tid < 128) qs[tid] = Qg[((long)bn << 7) + tid];
    for (int idx = tid; idx < NK * 128; idx += 256) {
        int j = idx >> 7, d = idx & 127;
        int ci = iter + 1, cj = 13 + iter - j;
        float c = (float)(ci < cj ? ci : cj);
        long g = ((long)(j * BN + bn) << 7) + d;
        Ks[j][d] = K[g] + c * pek[j * 128 + d];
        Vs[j][d] = V[g] + c * pev[j * 128 + d];
    }
    __syncthreads();
    for (int idx = tid; idx < 4 * NK; idx += 256) {
        int h = idx / NK, j = idx - h * NK;
        float s = 0.f;
#pragma unroll
        for (int d = 0; d < 32; ++d) s += qs[h * 32 + d] * Ks[j][h * 32 + d];
        sc[h][j] = s * 0.17677669529663687f;
    }
    __syncthreads();
    if (tid < 4) {
        float mx = -1e30f;
        for (int j = 0; j < NK; ++j) mx = fmaxf(mx, sc[tid][j]);
        float sum = 0.f;
        for (int j = 0; j < NK; ++j) { float e = expf(sc[tid][j] - mx); sc[tid][j] = e; sum += e; }
        float inv = 1.f / sum;
        for (int j = 0; j < NK; ++j) sc[tid][j] *= inv;
    }
    __syncthreads();
    if (tid < 128) {
        int h = tid >> 5;
        float s = 0.f;
        for (int j = 0; j < NK; ++j) s += sc[h][j] * Vs[j][tid];
        AOd[((long)bn << 7) + tid] = s;
    }
}

// ---------------------------------------------------------------------------
// u = X - relu(BACK); res = LN(u)*gamma + beta.  One wave per row of 128.
// ---------------------------------------------------------------------------
__global__ __launch_bounds__(256) void backcast_ln(
    const float* __restrict__ BACK, const float* __restrict__ X,
    const float* __restrict__ gamma, const float* __restrict__ beta,
    float* __restrict__ OUT) {
    int tid = threadIdx.x, lane = tid & 63, wv = tid >> 6;
    int row = blockIdx.x * 4 + wv;           // row = t*BN + bn
    int t = row >> 14, bn = row & 16383;
    int b = bn >> 9, n = bn & 511;
    long xoff = ((long)((b * 12 + t) * 512 + n) << 7) + lane * 2;
    float2 bk = *(const float2*)(BACK + ((long)row << 7) + lane * 2);
    float2 xv = *(const float2*)(X + xoff);
    float u0 = xv.x - fmaxf(bk.x, 0.f);
    float u1 = xv.y - fmaxf(bk.y, 0.f);
    float s = u0 + u1, sq = u0 * u0 + u1 * u1;
#pragma unroll
    for (int o = 32; o > 0; o >>= 1) { s += __shfl_xor(s, o); sq += __shfl_xor(sq, o); }
    float mu  = s * (1.f / 128.f);
    float var = sq * (1.f / 128.f) - mu * mu;
    float rs  = 1.f / sqrtf(var + 1e-5f);
    int d = lane * 2;
    float2 o;
    o.x = (u0 - mu) * rs * gamma[d] + beta[d];
    o.y = (u1 - mu) * rs * gamma[d + 1] + beta[d + 1];
    *(float2*)(OUT + xoff) = o;
}

// ---------------------------------------------------------------------------
// launch
// ---------------------------------------------------------------------------
extern "C" void kernel_launch(void* const* d_in, const int* in_sizes, int n_in,
                              void* d_out, int out_size, void* d_ws, size_t ws_size,
                              hipStream_t stream) {
    const float* X    = (const float*)d_in[0];
    const float* Wih  = (const float*)d_in[1];
    const float* Whh  = (const float*)d_in[2];
    const float* bih  = (const float*)d_in[3];
    const float* bhh  = (const float*)d_in[4];
    const float* Wqkv = (const float*)d_in[5];
    const float* bqkv = (const float*)d_in[6];
    const float* Wo   = (const float*)d_in[7];
    const float* bo   = (const float*)d_in[8];
    const float* Wb   = (const float*)d_in[9];
    const float* bb   = (const float*)d_in[10];
    const float* Wf   = (const float*)d_in[11];
    const float* bf   = (const float*)d_in[12];
    const float* gam  = (const float*)d_in[13];
    const float* bet  = (const float*)d_in[14];
    float* res = (float*)d_out;
    float* fc  = (float*)d_out + (long)BB * LL * NN * DD;

    float* w   = (float*)d_ws;
    float* pe  = w; w += 24 * 128;
    float* peq = w; w += 24 * 128;
    float* pek = w; w += 24 * 128;
    float* pev = w; w += 24 * 128;
    float* RNN = w; w += (long)LL * BN * DD;        // rnn_raw (L,BN,D)
    float* Kb  = w; w += (long)NSLOT * BN * DD;     // K base slots 0..22
    float* Vb  = w; w += (long)NSLOT * BN * DD;     // V base slots 0..22
    float* QA  = w; w += (long)LL * BN * DD;        // Q, then AO, then BACK (reused)
    float* Z0  = w; w += (long)LL * BN * DD;
    float* Qg  = w; w += (long)BN * DD;
    float* AOd = w; w += (long)BN * DD;
    float* G   = w; w += (long)2 * BN * DD;         // ping-pong gru outputs
    float* P   = w; w += (long)2 * BN * DD;         // ping-pong predictions

    const long CONT = 65536;                        // 512*128 => contiguous rows
    const long FOUT = (long)TT * NN * FKK;          // forecast outer stride

    pe_init<<<23, 128, 0, stream>>>(Wqkv, pe, peq, pek, pev);

    // ---- encoder GRU over L steps (output row t written in place of h) ----
    for (int t = 0; t < 12; ++t) {
        dim3 gr(BN / 64, 2);
        const float* xb = X + (long)t * NN * DD;
        if (t == 0)
            gru_step<true, false><<<gr, 256, 0, stream>>>(
                xb, (long)LL * NN * DD, nullptr, nullptr, Wih, Whh, bih, bhh, RNN);
        else
            gru_step<false, false><<<gr, 256, 0, stream>>>(
                xb, (long)LL * NN * DD, RNN + (long)(t - 1) * BN * DD, nullptr,
                Wih, Whh, bih, bhh, RNN + (long)t * BN * DD);
    }

    // ---- QKV of raw rnn states (PE folded in later via pe-projections) ----
    gemm_k128<<<dim3(LL * BN / 64, 6), 256, 0, stream>>>(
        RNN, CONT, Wqkv, bqkv, QA, Kb, Vb, CONT, 128);
    // ---- Z0 self-attention + out-proj ----
    attn_z0<<<BN, 256, 0, stream>>>(QA, Kb, Vb, peq, pek, pev, QA);
    gemm_k128<<<dim3(LL * BN / 64, 2), 256, 0, stream>>>(
        QA, CONT, Wo, bo, Z0, nullptr, nullptr, CONT, 128);

    // ---- backcast + residual LayerNorm -> res ----
    gemm_k128<<<dim3(LL * BN / 64, 2), 256, 0, stream>>>(
        Z0, CONT, Wb, bb, QA, nullptr, nullptr, CONT, 128);
    backcast_ln<<<LL * BN / 4, 256, 0, stream>>>(QA, X, gam, bet, res);

    // ---- forecast row t=0 from Z0[11] ----
    gemm_k128<<<dim3(BN / 64, 4), 256, 0, stream>>>(
        Z0 + (long)11 * BN * DD, CONT, Wf, bf, fc, fc + 128, nullptr, FOUT, FKK);

    // ---- decode loop ----
    for (int i = 0; i < 11; ++i) {
        float* g        = G + (long)(i & 1) * BN * DD;
        const float* gp = G + (long)((i - 1) & 1) * BN * DD;
        float* p        = P + (long)(i & 1) * BN * DD;
        const float* pp = P + (long)((i - 1) & 1) * BN * DD;
        const float* xsrc = (i == 0) ? Z0 + (long)11 * BN * DD : pp;
        dim3 gr(BN / 64, 2);
        if (i == 0)
            gru_step<false, false><<<gr, 256, 0, stream>>>(
                xsrc, CONT, RNN + (long)11 * BN * DD, nullptr, Wih, Whh, bih, bhh, g);
        else
            gru_step<false, true><<<gr, 256, 0, stream>>>(
                xsrc, CONT, gp, pe + (11 + i) * 128, Wih, Whh, bih, bhh, g);
        gemm_k128<<<dim3(BN / 64, 6), 256, 0, stream>>>(
            g, CONT, Wqkv, bqkv, Qg, Kb + (long)(12 + i) * BN * DD,
            Vb + (long)(12 + i) * BN * DD, CONT, 128);
        attn_dec<<<BN, 256, 0, stream>>>(Qg, Kb, Vb, pek, pev, AOd, 13 + i, i);
        gemm_k128<<<dim3(BN / 64, 2), 256, 0, stream>>>(
            AOd, CONT, Wo, bo, p, nullptr, nullptr, CONT, 128);
        gemm_k128<<<dim3(BN / 64, 4), 256, 0, stream>>>(
            p, CONT, Wf, bf, fc + (long)(i + 1) * NN * FKK,
            fc + (long)(i + 1) * NN * FKK + 128, nullptr, FOUT, FKK);
    }
}

// Round 3
// 5224.393 us; speedup vs baseline: 1.2087x; 1.2087x over previous
//
#include <hip/hip_runtime.h>
#include <hip/hip_bf16.h>
#include <math.h>

#define BB 32
#define LL 12
#define NN 512
#define DD 128
#define BN 16384
#define HH 4
#define TT 12
#define FKK 256
#define NSLOT 23

typedef __attribute__((ext_vector_type(8))) short short8v;
typedef __attribute__((ext_vector_type(4))) float f32x4;

// ---------------------------------------------------------------------------
// Exact 3-term bf16 truncation split: f == bf(s0)+bf(s1)+bf(s2) exactly
// (each step zeroes the captured high bits; residual subtraction is exact).
// ---------------------------------------------------------------------------
__device__ __forceinline__ void split3(float f, short& s0, short& s1, short& s2) {
    unsigned u = __builtin_bit_cast(unsigned, f);
    s0 = (short)(u >> 16);
    float f0 = __builtin_bit_cast(float, u & 0xFFFF0000u);
    float r1 = f - f0;
    unsigned u1 = __builtin_bit_cast(unsigned, r1);
    s1 = (short)(u1 >> 16);
    float f1 = __builtin_bit_cast(float, u1 & 0xFFFF0000u);
    s2 = (short)(__builtin_bit_cast(unsigned, r1 - f1) >> 16);
}

#define MFMA(A, B, C) __builtin_amdgcn_mfma_f32_16x16x32_bf16(A, B, C, 0, 0, 0)

// 6 significant cross-products of (a0+a1+a2)*(w0+w1+w2); dropped terms <=2^-24 rel.
__device__ __forceinline__ f32x4 mfma6(const short8v& a0, const short8v& a1,
                                       const short8v& a2, const short8v& w0,
                                       const short8v& w1, const short8v& w2,
                                       f32x4 acc) {
    acc = MFMA(a0, w2, acc);
    acc = MFMA(a2, w0, acc);
    acc = MFMA(a1, w1, acc);
    acc = MFMA(a0, w1, acc);
    acc = MFMA(a1, w0, acc);
    acc = MFMA(a0, w0, acc);
    return acc;
}

// Load one 16-row x 128-col A panel into triple-split frags.
// Lane l holds row (l&15), k = (l>>4)*8 + s*32 + e  (consistent for A and B).
__device__ __forceinline__ void load_frags(const float* __restrict__ base, long outer,
                                           long rowbase, int l15, int lg,
                                           const float* __restrict__ addv,
                                           short8v (&F0)[4], short8v (&F1)[4],
                                           short8v (&F2)[4]) {
    long row = rowbase + l15;
    const float* ap = base + (row >> 9) * outer + (row & 511) * 128 + lg * 8;
#pragma unroll
    for (int s = 0; s < 4; ++s) {
        float4 v0 = *(const float4*)(ap + s * 32);
        float4 v1 = *(const float4*)(ap + s * 32 + 4);
        if (addv) {
            const float4 a0 = *(const float4*)(addv + lg * 8 + s * 32);
            const float4 a1 = *(const float4*)(addv + lg * 8 + s * 32 + 4);
            v0.x += a0.x; v0.y += a0.y; v0.z += a0.z; v0.w += a0.w;
            v1.x += a1.x; v1.y += a1.y; v1.z += a1.z; v1.w += a1.w;
        }
        float f[8] = {v0.x, v0.y, v0.z, v0.w, v1.x, v1.y, v1.z, v1.w};
#pragma unroll
        for (int e = 0; e < 8; ++e) {
            short t0, t1, t2;
            split3(f[e], t0, t1, t2);
            F0[s][e] = t0; F1[s][e] = t1; F2[s][e] = t2;
        }
    }
}

// ---------------------------------------------------------------------------
// PE tables, double-precision to bit-match the numpy fp32 pipeline.
// ---------------------------------------------------------------------------
__global__ __launch_bounds__(128) void pe_init(const float* __restrict__ Wqkv,
                                               float* __restrict__ pe,
                                               float* __restrict__ peq,
                                               float* __restrict__ pek,
                                               float* __restrict__ pev) {
    int p = blockIdx.x, d = threadIdx.x;
    __shared__ float per[128];
    int i2 = (d >> 1) << 1;
    float sf = (float)(-::log(10000.0) / 128.0);
    float x = (float)i2 * sf;                 // numpy: f32 multiply
    float div = (float)::exp((double)x);      // numpy: correctly-rounded exp(f32)
    float arg = (float)p * div;               // f32 multiply
    per[d] = (d & 1) ? (float)::cos((double)arg) : (float)::sin((double)arg);
    __syncthreads();
    pe[p * 128 + d] = per[d];
    float sq = 0.f, sk = 0.f, sv = 0.f;
    for (int k = 0; k < 128; ++k) {
        float pv = per[k];
        sq += pv * Wqkv[d * 128 + k];
        sk += pv * Wqkv[(128 + d) * 128 + k];
        sv += pv * Wqkv[(256 + d) * 128 + k];
    }
    peq[p * 128 + d] = sq;
    pek[p * 128 + d] = sk;
    pev[p * 128 + d] = sv;
}

// ---------------------------------------------------------------------------
// Weight prep: triple-split all weights into bf16 planes (row-concatenated).
// rows: [0,384) Wih | [384,768) Whh | [768,1152) Wqkv | [1152,1280) Wo
//       | [1280,1408) Wb | [1408,1664) Wf
// ---------------------------------------------------------------------------
__global__ __launch_bounds__(256) void wprep(
    const float* __restrict__ Wih, const float* __restrict__ Whh,
    const float* __restrict__ Wqkv, const float* __restrict__ Wo,
    const float* __restrict__ Wb, const float* __restrict__ Wf,
    short* __restrict__ W0, short* __restrict__ W1, short* __restrict__ W2) {
    int idx = blockIdx.x * 256 + threadIdx.x;
    int row = idx >> 7;
    const float* src; int r0;
    if (row < 384) { src = Wih; r0 = 0; }
    else if (row < 768) { src = Whh; r0 = 384; }
    else if (row < 1152) { src = Wqkv; r0 = 768; }
    else if (row < 1280) { src = Wo; r0 = 1152; }
    else if (row < 1408) { src = Wb; r0 = 1280; }
    else { src = Wf; r0 = 1408; }
    float f = src[idx - (r0 << 7)];
    short t0, t1, t2;
    split3(f, t0, t1, t2);
    W0[idx] = t0; W1[idx] = t1; W2[idx] = t2;
}

// ---------------------------------------------------------------------------
// Generic GEMM: C = A @ W^T + bias via 6-pass split MFMA.
// Block: 4 waves x 16 rows = 64 rows. Col frags [blockIdx.y*CFPB, +CFPB).
// Output 128-col groups routed to C0/C1/C2.
// ---------------------------------------------------------------------------
template <int NC, int CFPB>
__global__ __launch_bounds__(256) void mfma_gemm(
    const float* __restrict__ A, long a_outer,
    const short* __restrict__ W0, const short* __restrict__ W1,
    const short* __restrict__ W2, const float* __restrict__ bias,
    float* __restrict__ C0, float* __restrict__ C1, float* __restrict__ C2,
    long c_outer, long c_inner) {
    int tid = threadIdx.x, lane = tid & 63, wid = tid >> 6;
    int l15 = lane & 15, lg = lane >> 4;
    long rowbase = (long)blockIdx.x * 64 + wid * 16;
    short8v A0[4], A1[4], A2[4];
    load_frags(A, a_outer, rowbase, l15, lg, nullptr, A0, A1, A2);
    int cfbeg = blockIdx.y * CFPB;
#pragma unroll 2
    for (int cf = 0; cf < CFPB; ++cf) {
        int colg = (cfbeg + cf) * 16;
        long woff = (long)(colg + l15) * 128 + lg * 8;
        f32x4 acc = {0.f, 0.f, 0.f, 0.f};
#pragma unroll
        for (int s = 0; s < 4; ++s) {
            short8v w0 = *(const short8v*)(W0 + woff + s * 32);
            short8v w1 = *(const short8v*)(W1 + woff + s * 32);
            short8v w2 = *(const short8v*)(W2 + woff + s * 32);
            acc = mfma6(A0[s], A1[s], A2[s], w0, w1, w2, acc);
        }
        float b = bias[colg + l15];
        float* Cp; int cc = colg + l15;
        if (NC > 256 && colg >= 256) { Cp = C2; cc -= 256; }
        else if (NC > 128 && colg >= 128) { Cp = C1; cc -= 128; }
        else { Cp = C0; }
#pragma unroll
        for (int r = 0; r < 4; ++r) {
            long row = rowbase + 4 * lg + r;
            Cp[(row >> 9) * c_outer + (row & 511) * c_inner + cc] = acc[r] + b;
        }
    }
}

// ---------------------------------------------------------------------------
// Fused GRU step via 6-pass split MFMA. Block: 4 waves x 16 rows = 64 rows.
// Per wave: x,h frags resident (split once), loop 8 col-groups of 16.
// r,z accumulate gi+gh together; n keeps gi/gh separate for r*(...) form.
// ---------------------------------------------------------------------------
template <bool HZERO, bool HADD>
__global__ __launch_bounds__(256) void mfma_gru(
    const float* __restrict__ Xb, long x_outer,
    const float* __restrict__ Hb, const float* __restrict__ hadd,
    const short* __restrict__ Wi0, const short* __restrict__ Wi1,
    const short* __restrict__ Wi2,   // Wih splits (384 rows)
    const short* __restrict__ Wh0, const short* __restrict__ Wh1,
    const short* __restrict__ Wh2,   // Whh splits
    const float* __restrict__ bih, const float* __restrict__ bhh,
    float* __restrict__ Hout) {
    int tid = threadIdx.x, lane = tid & 63, wid = tid >> 6;
    int l15 = lane & 15, lg = lane >> 4;
    long rowbase = (long)blockIdx.x * 64 + wid * 16;
    short8v X0[4], X1[4], X2[4];
    short8v H0[4], H1[4], H2[4];
    load_frags(Xb, x_outer, rowbase, l15, lg, nullptr, X0, X1, X2);
    if (!HZERO)
        load_frags(Hb, 65536, rowbase, l15, lg, HADD ? hadd : nullptr, H0, H1, H2);
#pragma unroll 1
    for (int cg = 0; cg < 8; ++cg) {
        int d = cg * 16 + l15;
        f32x4 ar = {0.f, 0.f, 0.f, 0.f};   // gi_r + gh_r
        f32x4 az = {0.f, 0.f, 0.f, 0.f};   // gi_z + gh_z
        f32x4 an = {0.f, 0.f, 0.f, 0.f};   // gi_n
        f32x4 ahn = {0.f, 0.f, 0.f, 0.f};  // gh_n
        long wr = (long)d * 128 + lg * 8;
        long wz = (long)(128 + d) * 128 + lg * 8;
        long wn = (long)(256 + d) * 128 + lg * 8;
#pragma unroll
        for (int s = 0; s < 4; ++s) {
            int so = s * 32;
            {
                short8v w0 = *(const short8v*)(Wi0 + wr + so);
                short8v w1 = *(const short8v*)(Wi1 + wr + so);
                short8v w2 = *(const short8v*)(Wi2 + wr + so);
                ar = mfma6(X0[s], X1[s], X2[s], w0, w1, w2, ar);
            }
            {
                short8v w0 = *(const short8v*)(Wi0 + wz + so);
                short8v w1 = *(const short8v*)(Wi1 + wz + so);
                short8v w2 = *(const short8v*)(Wi2 + wz + so);
                az = mfma6(X0[s], X1[s], X2[s], w0, w1, w2, az);
            }
            {
                short8v w0 = *(const short8v*)(Wi0 + wn + so);
                short8v w1 = *(const short8v*)(Wi1 + wn + so);
                short8v w2 = *(const short8v*)(Wi2 + wn + so);
                an = mfma6(X0[s], X1[s], X2[s], w0, w1, w2, an);
            }
            if (!HZERO) {
                {
                    short8v w0 = *(const short8v*)(Wh0 + wr + so);
                    short8v w1 = *(const short8v*)(Wh1 + wr + so);
                    short8v w2 = *(const short8v*)(Wh2 + wr + so);
                    ar = mfma6(H0[s], H1[s], H2[s], w0, w1, w2, ar);
                }
                {
                    short8v w0 = *(const short8v*)(Wh0 + wz + so);
                    short8v w1 = *(const short8v*)(Wh1 + wz + so);
                    short8v w2 = *(const short8v*)(Wh2 + wz + so);
                    az = mfma6(H0[s], H1[s], H2[s], w0, w1, w2, az);
                }
                {
                    short8v w0 = *(const short8v*)(Wh0 + wn + so);
                    short8v w1 = *(const short8v*)(Wh1 + wn + so);
                    short8v w2 = *(const short8v*)(Wh2 + wn + so);
                    ahn = mfma6(H0[s], H1[s], H2[s], w0, w1, w2, ahn);
                }
            }
        }
        float bi0 = bih[d], bi1 = bih[128 + d], bi2 = bih[256 + d];
        float bh0 = bhh[d], bh1 = bhh[128 + d], bh2 = bhh[256 + d];
#pragma unroll
        for (int r = 0; r < 4; ++r) {
            long row = rowbase + 4 * lg + r;
            float hp = 0.f;
            if (!HZERO) {
                hp = Hb[row * 128 + d];
                if (HADD) hp += hadd[d];
            }
            float rr = 1.f / (1.f + expf(-(ar[r] + bi0 + bh0)));
            float zz = 1.f / (1.f + expf(-(az[r] + bi1 + bh1)));
            float hn = bh2 + (HZERO ? 0.f : ahn[r]);
            float nn = tanhf(an[r] + bi2 + rr * hn);
            Hout[row * 128 + d] = (1.f - zz) * nn + zz * hp;
        }
    }
}

// ---------------------------------------------------------------------------
// Z0 self-attention (12x12), PE folded via precomputed pe-projections.
// ---------------------------------------------------------------------------
__global__ __launch_bounds__(256) void attn_z0(
    const float* Q, const float* __restrict__ K, const float* __restrict__ V,
    const float* __restrict__ peq, const float* __restrict__ pek,
    const float* __restrict__ pev, float* AO) {
    int bn = blockIdx.x, tid = threadIdx.x;
    __shared__ float Qs[12][132], Ks[12][132], Vs[12][132];
    __shared__ float sc[4][12][12];
    for (int idx = tid; idx < 12 * 128; idx += 256) {
        int t = idx >> 7, d = idx & 127;
        long g = ((long)(t * BN + bn) << 7) + d;
        Qs[t][d] = Q[g] + peq[t * 128 + d];
        Ks[t][d] = K[g] + pek[t * 128 + d];
        Vs[t][d] = V[g] + pev[t * 128 + d];
    }
    __syncthreads();
    for (int idx = tid; idx < 576; idx += 256) {
        int h = idx / 144, r = idx - h * 144;
        int q = r / 12, k = r - (r / 12) * 12;
        float s = 0.f;
#pragma unroll
        for (int d = 0; d < 32; ++d) s += Qs[q][h * 32 + d] * Ks[k][h * 32 + d];
        sc[h][q][k] = s * 0.17677669529663687f;
    }
    __syncthreads();
    if (tid < 48) {
        int h = tid / 12, q = tid - (tid / 12) * 12;
        float mx = sc[h][q][0];
#pragma unroll
        for (int k = 1; k < 12; ++k) mx = fmaxf(mx, sc[h][q][k]);
        float sum = 0.f;
#pragma unroll
        for (int k = 0; k < 12; ++k) { float e = expf(sc[h][q][k] - mx); sc[h][q][k] = e; sum += e; }
        float inv = 1.f / sum;
#pragma unroll
        for (int k = 0; k < 12; ++k) sc[h][q][k] *= inv;
    }
    __syncthreads();
    for (int idx = tid; idx < 1536; idx += 256) {
        int q = idx >> 7, d = idx & 127, h = d >> 5;
        float s = 0.f;
#pragma unroll
        for (int k = 0; k < 12; ++k) s += sc[h][q][k] * Vs[k][d];
        AO[((long)(q * BN + bn) << 7) + d] = s;
    }
}

// ---------------------------------------------------------------------------
// Decode attention: 1 query vs NK keys; PE folded via c_j = min(iter+1,13+iter-j).
// ---------------------------------------------------------------------------
__global__ __launch_bounds__(256) void attn_dec(
    const float* __restrict__ Qg, const float* __restrict__ K,
    const float* __restrict__ V, const float* __restrict__ pek,
    const float* __restrict__ pev, float* __restrict__ AOd, int NK, int iter) {
    int bn = blockIdx.x, tid = threadIdx.x;
    __shared__ float qs[128];
    __shared__ float Ks[NSLOT][132], Vs[NSLOT][132];
    __shared__ float sc[4][NSLOT];
    if (tid < 128) qs[tid] = Qg[((long)bn << 7) + tid];
    for (int idx = tid; idx < NK * 128; idx += 256) {
        int j = idx >> 7, d = idx & 127;
        int ci = iter + 1, cj = 13 + iter - j;
        float c = (float)(ci < cj ? ci : cj);
        long g = ((long)(j * BN + bn) << 7) + d;
        Ks[j][d] = K[g] + c * pek[j * 128 + d];
        Vs[j][d] = V[g] + c * pev[j * 128 + d];
    }
    __syncthreads();
    for (int idx = tid; idx < 4 * NK; idx += 256) {
        int h = idx / NK, j = idx - h * NK;
        float s = 0.f;
#pragma unroll
        for (int d = 0; d < 32; ++d) s += qs[h * 32 + d] * Ks[j][h * 32 + d];
        sc[h][j] = s * 0.17677669529663687f;
    }
    __syncthreads();
    if (tid < 4) {
        float mx = -1e30f;
        for (int j = 0; j < NK; ++j) mx = fmaxf(mx, sc[tid][j]);
        float sum = 0.f;
        for (int j = 0; j < NK; ++j) { float e = expf(sc[tid][j] - mx); sc[tid][j] = e; sum += e; }
        float inv = 1.f / sum;
        for (int j = 0; j < NK; ++j) sc[tid][j] *= inv;
    }
    __syncthreads();
    if (tid < 128) {
        int h = tid >> 5;
        float s = 0.f;
        for (int j = 0; j < NK; ++j) s += sc[h][j] * Vs[j][tid];
        AOd[((long)bn << 7) + tid] = s;
    }
}

// ---------------------------------------------------------------------------
// u = X - relu(BACK); res = LN(u)*gamma + beta.
// ---------------------------------------------------------------------------
__global__ __launch_bounds__(256) void backcast_ln(
    const float* __restrict__ BACK, const float* __restrict__ X,
    const float* __restrict__ gamma, const float* __restrict__ beta,
    float* __restrict__ OUT) {
    int tid = threadIdx.x, lane = tid & 63, wv = tid >> 6;
    int row = blockIdx.x * 4 + wv;
    int t = row >> 14, bn = row & 16383;
    int b = bn >> 9, n = bn & 511;
    long xoff = ((long)((b * 12 + t) * 512 + n) << 7) + lane * 2;
    float2 bk = *(const float2*)(BACK + ((long)row << 7) + lane * 2);
    float2 xv = *(const float2*)(X + xoff);
    float u0 = xv.x - fmaxf(bk.x, 0.f);
    float u1 = xv.y - fmaxf(bk.y, 0.f);
    float s = u0 + u1, sq = u0 * u0 + u1 * u1;
#pragma unroll
    for (int o = 32; o > 0; o >>= 1) { s += __shfl_xor(s, o); sq += __shfl_xor(sq, o); }
    float mu = s * (1.f / 128.f);
    float var = sq * (1.f / 128.f) - mu * mu;
    float rs = 1.f / sqrtf(var + 1e-5f);
    int d = lane * 2;
    float2 o;
    o.x = (u0 - mu) * rs * gamma[d] + beta[d];
    o.y = (u1 - mu) * rs * gamma[d + 1] + beta[d + 1];
    *(float2*)(OUT + xoff) = o;
}

// ---------------------------------------------------------------------------
// launch
// ---------------------------------------------------------------------------
extern "C" void kernel_launch(void* const* d_in, const int* in_sizes, int n_in,
                              void* d_out, int out_size, void* d_ws, size_t ws_size,
                              hipStream_t stream) {
    const float* X    = (const float*)d_in[0];
    const float* Wih  = (const float*)d_in[1];
    const float* Whh  = (const float*)d_in[2];
    const float* bih  = (const float*)d_in[3];
    const float* bhh  = (const float*)d_in[4];
    const float* Wqkv = (const float*)d_in[5];
    const float* bqkv = (const float*)d_in[6];
    const float* Wo   = (const float*)d_in[7];
    const float* bo   = (const float*)d_in[8];
    const float* Wb   = (const float*)d_in[9];
    const float* bb   = (const float*)d_in[10];
    const float* Wf   = (const float*)d_in[11];
    const float* bf   = (const float*)d_in[12];
    const float* gam  = (const float*)d_in[13];
    const float* bet  = (const float*)d_in[14];
    float* res = (float*)d_out;
    float* fc  = (float*)d_out + (long)BB * LL * NN * DD;

    const long WROWS = 1664;
    short* Wsp0 = (short*)d_ws;
    short* Wsp1 = Wsp0 + WROWS * 128;
    short* Wsp2 = Wsp1 + WROWS * 128;
    float* w   = (float*)(Wsp2 + WROWS * 128);   // 1664*128*3*2 B = 1,277,952 (16B-mult)
    float* pe  = w; w += 24 * 128;
    float* peq = w; w += 24 * 128;
    float* pek = w; w += 24 * 128;
    float* pev = w; w += 24 * 128;
    float* RNN = w; w += (long)LL * BN * DD;
    float* Kb  = w; w += (long)NSLOT * BN * DD;
    float* Vb  = w; w += (long)NSLOT * BN * DD;
    float* QA  = w; w += (long)LL * BN * DD;
    float* Z0  = w; w += (long)LL * BN * DD;
    float* Qg  = w; w += (long)BN * DD;
    float* AOd = w; w += (long)BN * DD;
    float* G   = w; w += (long)2 * BN * DD;
    float* P   = w; w += (long)2 * BN * DD;

    // weight row offsets within the split planes
    const short* wih0 = Wsp0,        * wih1 = Wsp1,        * wih2 = Wsp2;
    const short* whh0 = Wsp0 + 384 * 128, * whh1 = Wsp1 + 384 * 128, * whh2 = Wsp2 + 384 * 128;
    const short* wqk0 = Wsp0 + 768 * 128, * wqk1 = Wsp1 + 768 * 128, * wqk2 = Wsp2 + 768 * 128;
    const short* wo0  = Wsp0 + 1152 * 128, * wo1 = Wsp1 + 1152 * 128, * wo2 = Wsp2 + 1152 * 128;
    const short* wb0  = Wsp0 + 1280 * 128, * wb1 = Wsp1 + 1280 * 128, * wb2 = Wsp2 + 1280 * 128;
    const short* wf0  = Wsp0 + 1408 * 128, * wf1 = Wsp1 + 1408 * 128, * wf2 = Wsp2 + 1408 * 128;

    const long CONT = 65536;
    const long FOUT = (long)TT * NN * FKK;

    pe_init<<<24, 128, 0, stream>>>(Wqkv, pe, peq, pek, pev);
    wprep<<<832, 256, 0, stream>>>(Wih, Whh, Wqkv, Wo, Wb, Wf, Wsp0, Wsp1, Wsp2);

    // ---- encoder GRU over L steps ----
    for (int t = 0; t < 12; ++t) {
        const float* xb = X + (long)t * NN * DD;
        if (t == 0)
            mfma_gru<true, false><<<256, 256, 0, stream>>>(
                xb, (long)LL * NN * DD, nullptr, nullptr,
                wih0, wih1, wih2, whh0, whh1, whh2, bih, bhh, RNN);
        else
            mfma_gru<false, false><<<256, 256, 0, stream>>>(
                xb, (long)LL * NN * DD, RNN + (long)(t - 1) * BN * DD, nullptr,
                wih0, wih1, wih2, whh0, whh1, whh2, bih, bhh,
                RNN + (long)t * BN * DD);
    }

    // ---- QKV of raw rnn states ----
    mfma_gemm<384, 24><<<dim3(3072, 1), 256, 0, stream>>>(
        RNN, CONT, wqk0, wqk1, wqk2, bqkv, QA, Kb, Vb, CONT, 128);
    // ---- Z0 self-attention + out-proj ----
    attn_z0<<<BN, 256, 0, stream>>>(QA, Kb, Vb, peq, pek, pev, QA);
    mfma_gemm<128, 8><<<dim3(3072, 1), 256, 0, stream>>>(
        QA, CONT, wo0, wo1, wo2, bo, Z0, nullptr, nullptr, CONT, 128);

    // ---- backcast + residual LayerNorm ----
    mfma_gemm<128, 8><<<dim3(3072, 1), 256, 0, stream>>>(
        Z0, CONT, wb0, wb1, wb2, bb, QA, nullptr, nullptr, CONT, 128);
    backcast_ln<<<LL * BN / 4, 256, 0, stream>>>(QA, X, gam, bet, res);

    // ---- forecast row t=0 from Z0[11] ----
    mfma_gemm<256, 8><<<dim3(256, 2), 256, 0, stream>>>(
        Z0 + (long)11 * BN * DD, CONT, wf0, wf1, wf2, bf, fc, fc + 128, nullptr,
        FOUT, FKK);

    // ---- decode loop ----
    for (int i = 0; i < 11; ++i) {
        float* g        = G + (long)(i & 1) * BN * DD;
        const float* gp = G + (long)((i - 1) & 1) * BN * DD;
        float* p        = P + (long)(i & 1) * BN * DD;
        const float* pp = P + (long)((i - 1) & 1) * BN * DD;
        const float* xsrc = (i == 0) ? Z0 + (long)11 * BN * DD : pp;
        if (i == 0)
            mfma_gru<false, false><<<256, 256, 0, stream>>>(
                xsrc, CONT, RNN + (long)11 * BN * DD, nullptr,
                wih0, wih1, wih2, whh0, whh1, whh2, bih, bhh, g);
        else
            mfma_gru<false, true><<<256, 256, 0, stream>>>(
                xsrc, CONT, gp, pe + (11 + i) * 128,
                wih0, wih1, wih2, whh0, whh1, whh2, bih, bhh, g);
        mfma_gemm<384, 12><<<dim3(256, 2), 256, 0, stream>>>(
            g, CONT, wqk0, wqk1, wqk2, bqkv, Qg, Kb + (long)(12 + i) * BN * DD,
            Vb + (long)(12 + i) * BN * DD, CONT, 128);
        attn_dec<<<BN, 256, 0, stream>>>(Qg, Kb, Vb, pek, pev, AOd, 13 + i, i);
        mfma_gemm<128, 4><<<dim3(256, 2), 256, 0, stream>>>(
            AOd, CONT, wo0, wo1, wo2, bo, p, nullptr, nullptr, CONT, 128);
        mfma_gemm<256, 8><<<dim3(256, 2), 256, 0, stream>>>(
            p, CONT, wf0, wf1, wf2, bf, fc + (long)(i + 1) * NN * FKK,
            fc + (long)(i + 1) * NN * FKK + 128, nullptr, FOUT, FKK);
    }
}